// Round 1
// baseline (1785.512 us; speedup 1.0000x reference)
//
#include <hip/hip_runtime.h>

typedef _Float16 h2   __attribute__((ext_vector_type(2)));
typedef _Float16 h4   __attribute__((ext_vector_type(4)));
typedef _Float16 half8 __attribute__((ext_vector_type(8)));
typedef float f32x4   __attribute__((ext_vector_type(4)));

#define MFMA16(a,b,c) __builtin_amdgcn_mfma_f32_16x16x32_f16((a),(b),(c),0,0,0)

// Problem sizes (hardcoded per reference)
// B=512, T=64, STOCH=30, DETER=200, HIDDEN=200, A=12, EMBED=1024
// out row = [stoch_po(30), mean_po(30), std_po(30), stoch_pr(30), mean_pr(30), std_pr(30), deter(200)] = 380

// Fragment regions (blocks of 64 lanes x 8 halves = 1KB each), B-frag order [nt][ks][lane][8]
// INP:  NT=13 KS=2  (K=42->64,  N=200->208)   base 0    (26 blocks)
// GRU:  NT=38 KS=13 (K=400->416,N=600->608)   base 26   (494)
// IMG:  NT=13 KS=7  (K=200->224,N=200->208)   base 520  (91)
// OBSD: NT=13 KS=7  (K=200->224,N=200->208)   base 611  (91)
// IMS:  NT=4  KS=7  (K=200->224,N=60->64)     base 702  (28)
// OBS:  NT=4  KS=7  (K=200->224,N=60->64)     base 730  (28)
// W2:   NT=13 KS=32 (K=1024,   N=200->208)    base 758  (416)  -> total 1174 blocks
#define EP_HALVES ((size_t)32768*208)

__global__ void prep_frags(const float* __restrict__ inpW, const float* __restrict__ gruW,
                           const float* __restrict__ imgW, const float* __restrict__ obsoutW,
                           const float* __restrict__ imsW, const float* __restrict__ obsW,
                           _Float16* __restrict__ frags) {
    int gb = blockIdx.x, lane = threadIdx.x;
    const float* src; int KS, K, N, ld, roff = 0, local;
    if (gb < 26)       { src = inpW;    KS = 2;  K = 42;   N = 200; ld = 200; local = gb; }
    else if (gb < 520) { src = gruW;    KS = 13; K = 400;  N = 600; ld = 600; local = gb - 26; }
    else if (gb < 611) { src = imgW;    KS = 7;  K = 200;  N = 200; ld = 200; local = gb - 520; }
    else if (gb < 702) { src = obsoutW; KS = 7;  K = 200;  N = 200; ld = 200; local = gb - 611; }
    else if (gb < 730) { src = imsW;    KS = 7;  K = 200;  N = 60;  ld = 60;  local = gb - 702; }
    else if (gb < 758) { src = obsW;    KS = 7;  K = 200;  N = 60;  ld = 60;  local = gb - 730; }
    else               { src = obsoutW; KS = 32; K = 1024; N = 200; ld = 200; roff = 200; local = gb - 758; }
    int nt = local / KS, ks = local % KS;
    int n  = nt * 16 + (lane & 15);
    int k0 = ks * 32 + (lane >> 4) * 8;
    half8 v;
#pragma unroll
    for (int j = 0; j < 8; ++j) {
        int k = k0 + j;
        float f = (k < K && n < N) ? src[(size_t)(k + roff) * ld + n] : 0.0f;
        v[j] = (_Float16)f;
    }
    *(half8*)(frags + (size_t)gb * 512 + lane * 8) = v;
}

// ep[row][0..207] = embed[row] @ obs_out_W[200:,:]   (f16 out), row = b*64+t
__global__ __launch_bounds__(256) void ep_gemm(const float* __restrict__ embed,
                                               const _Float16* __restrict__ w2f,
                                               _Float16* __restrict__ ep) {
    __shared__ __align__(16) _Float16 aE[16 * 1048];   // stride 1048 f16 (524 dw, 2-way banks)
    int tid = threadIdx.x;
    int rb = blockIdx.x * 16;
    for (int i = 0; i < 16; ++i) {
        float4 e = *((const float4*)(embed + (size_t)(rb + i) * 1024) + tid);
        h4 hv; hv[0] = (_Float16)e.x; hv[1] = (_Float16)e.y; hv[2] = (_Float16)e.z; hv[3] = (_Float16)e.w;
        *(h4*)(aE + i * 1048 + tid * 4) = hv;
    }
    __syncthreads();
    int w = tid >> 6, lane = tid & 63, m = lane & 15, q = lane >> 4;
    f32x4 acc[4] = {};
    int nts[4]; int ntc = 0;
    for (int nt = w; nt < 13; nt += 4) nts[ntc++] = nt;
    for (int ks = 0; ks < 32; ++ks) {
        half8 a = *(const half8*)(aE + m * 1048 + ks * 32 + q * 8);
#pragma unroll
        for (int j = 0; j < 4; ++j) if (j < ntc) {
            half8 b = *(const half8*)(w2f + ((size_t)(nts[j] * 32 + ks) * 64 + lane) * 8);
            acc[j] = MFMA16(a, b, acc[j]);
        }
    }
    for (int j = 0; j < ntc; ++j) {
        int col = nts[j] * 16 + m;
#pragma unroll
        for (int i = 0; i < 4; ++i)
            ep[(size_t)(rb + q * 4 + i) * 208 + col] = (_Float16)acc[j][i];
    }
}

__device__ __forceinline__ float sigm_(float x) { return 1.0f / (1.0f + __expf(-x)); }
__device__ __forceinline__ float tanh_(float x) { float e = __expf(2.0f * x); return 1.0f - 2.0f / (e + 1.0f); }
__device__ __forceinline__ float elu_(float x)  { return x > 0.0f ? x : __expf(x) - 1.0f; }
__device__ __forceinline__ float sp_(float x)   { return fmaxf(x, 0.0f) + log1pf(__expf(-fabsf(x))); }

// One WG = 16 batch rows, all 64 steps. 32 WGs cover B=512.
__global__ __launch_bounds__(512) void rssm_scan(
    const float* __restrict__ action, const float* __restrict__ npr, const float* __restrict__ npo,
    const float* __restrict__ inp_b, const float* __restrict__ gru_b,
    const float* __restrict__ img_b, const float* __restrict__ obsout_b,
    const float* __restrict__ ims_b, const float* __restrict__ obs_b,
    const _Float16* __restrict__ frags, const _Float16* __restrict__ ep,
    float* __restrict__ out) {

    // LDS: packed f16-pair activation arrays (dword units) + f16 matmul-out scratch + biases (~55.7KB)
    __shared__ __align__(16) unsigned actI[16 * 36];    // [stoch(15p) action(6p) pad->32p], stride 36dw
    __shared__ __align__(16) unsigned actG[16 * 212];   // [x(100p) deter(100p) pad->212dw]
    __shared__ __align__(16) unsigned actH[16 * 116];   // h   (100p + pad)
    __shared__ __align__(16) unsigned actHO[16 * 116];  // ho
    __shared__ __align__(16) _Float16 parts[16 * 616];  // matmul outputs (f16), stride 616
    __shared__ float bias[1320];  // inp200 | gru600 | img200 | obsout200 | ims60 | obs60

    const _Float16* Finp  = frags;
    const _Float16* Fgru  = frags + (size_t)26  * 512;
    const _Float16* Fimg  = frags + (size_t)520 * 512;
    const _Float16* Fobsd = frags + (size_t)611 * 512;
    const _Float16* Fims  = frags + (size_t)702 * 512;
    const _Float16* Fobs  = frags + (size_t)730 * 512;

    int tid = threadIdx.x;
    int w = tid >> 6, lane = tid & 63, m = lane & 15, q = lane >> 4;
    int rb = blockIdx.x * 16;

    for (int i = tid; i < 1320; i += 512) {
        float v;
        if (i < 200) v = inp_b[i];
        else if (i < 800)  v = gru_b[i - 200];
        else if (i < 1000) v = img_b[i - 800];
        else if (i < 1200) v = obsout_b[i - 1000];
        else if (i < 1260) v = ims_b[i - 1200];
        else               v = obs_b[i - 1260];
        bias[i] = v;
    }
    for (int i = tid; i < 16 * 36;  i += 512) actI[i] = 0u;
    for (int i = tid; i < 16 * 212; i += 512) actG[i] = 0u;
    for (int i = tid; i < 16 * 116; i += 512) { actH[i] = 0u; actHO[i] = 0u; }
    __syncthreads();

    for (int t = 0; t < 64; ++t) {
        // P0: pack action into actI pairs 15..20
        if (tid < 96) {
            int r = tid / 6, cp = tid % 6;
            float2 a2 = *(const float2*)(action + ((size_t)(rb + r) * 64 + t) * 12 + 2 * cp);
            h2 p; p[0] = (_Float16)a2.x; p[1] = (_Float16)a2.y;
            *(h2*)&actI[r * 36 + 15 + cp] = p;
        }
        __syncthreads();

        // P1: x preact = cat(stoch, action) @ inp_W   (NT=13, KS=2)
        {
            f32x4 acc[2] = {};
            int nts[2]; int ntc = 0;
            for (int nt = w; nt < 13; nt += 8) nts[ntc++] = nt;
            for (int ks = 0; ks < 2; ++ks) {
                half8 a = *(const half8*)(actI + m * 36 + ks * 16 + q * 4);
#pragma unroll
                for (int j = 0; j < 2; ++j) if (j < ntc) {
                    half8 b = *(const half8*)(Finp + ((size_t)(nts[j] * 2 + ks) * 64 + lane) * 8);
                    acc[j] = MFMA16(a, b, acc[j]);
                }
            }
            for (int j = 0; j < ntc; ++j)
#pragma unroll
                for (int i = 0; i < 4; ++i)
                    parts[(q * 4 + i) * 616 + nts[j] * 16 + m] = (_Float16)acc[j][i];
        }
        __syncthreads();

        // pack-x: x = elu(preact + inp_b) -> actG pairs 0..99
        for (int idx = tid; idx < 1600; idx += 512) {
            int r = idx / 100, cp = idx % 100;
            h2 v = *(const h2*)(parts + r * 616 + 2 * cp);
            float v0 = elu_((float)v[0] + bias[2 * cp]);
            float v1 = elu_((float)v[1] + bias[2 * cp + 1]);
            h2 p; p[0] = (_Float16)v0; p[1] = (_Float16)v1;
            *(h2*)&actG[r * 212 + cp] = p;
        }
        __syncthreads();

        // P2: parts = cat(x, deter) @ gru_W   (NT=38, KS=13)
        {
            f32x4 acc[5] = {};
            int nts[5]; int ntc = 0;
            for (int nt = w; nt < 38; nt += 8) nts[ntc++] = nt;
            for (int ks = 0; ks < 13; ++ks) {
                half8 a = *(const half8*)(actG + m * 212 + ks * 16 + q * 4);
#pragma unroll
                for (int j = 0; j < 5; ++j) if (j < ntc) {
                    half8 b = *(const half8*)(Fgru + ((size_t)(nts[j] * 13 + ks) * 64 + lane) * 8);
                    acc[j] = MFMA16(a, b, acc[j]);
                }
            }
            for (int j = 0; j < ntc; ++j)
#pragma unroll
                for (int i = 0; i < 4; ++i)
                    parts[(q * 4 + i) * 616 + nts[j] * 16 + m] = (_Float16)acc[j][i];
        }
        __syncthreads();

        // gates: GRU update -> deter_new (packed into actG pairs 100..199) + out[180..379]
        for (int idx = tid; idx < 1600; idx += 512) {
            int r = idx / 100, cp = idx % 100;
            const _Float16* pr = parts + r * 616;
            h2 p0 = *(const h2*)(pr + 2 * cp);
            h2 p1 = *(const h2*)(pr + 200 + 2 * cp);
            h2 p2 = *(const h2*)(pr + 400 + 2 * cp);
            h2 dold = *(const h2*)&actG[r * 212 + 100 + cp];
            float dn[2];
#pragma unroll
            for (int e = 0; e < 2; ++e) {
                int n = 2 * cp + e;
                float reset = sigm_((float)p0[e] + bias[200 + n]);
                float cand  = tanh_(reset * ((float)p1[e] + bias[400 + n]));
                float upd   = sigm_((float)p2[e] + bias[600 + n] - 1.0f);
                dn[e] = upd * cand + (1.0f - upd) * (float)dold[e];
            }
            h2 pk; pk[0] = (_Float16)dn[0]; pk[1] = (_Float16)dn[1];
            *(h2*)&actG[r * 212 + 100 + cp] = pk;
            *(float2*)(out + ((size_t)(rb + r) * 64 + t) * 380 + 180 + 2 * cp) = make_float2(dn[0], dn[1]);
        }
        __syncthreads();

        // P3: h-preact = deter_new @ img_out_W ; ho-preact = deter_new @ obs_out_W[:200]  (26 tiles, KS=7)
        {
            f32x4 acc[4] = {};
            int nts[4]; int ntc = 0;
            for (int nt = w; nt < 26; nt += 8) nts[ntc++] = nt;
            for (int ks = 0; ks < 7; ++ks) {
                half8 a = *(const half8*)(actG + m * 212 + 100 + ks * 16 + q * 4);
#pragma unroll
                for (int j = 0; j < 4; ++j) if (j < ntc) {
                    int nt = nts[j];
                    const _Float16* F = (nt < 13) ? Fimg : Fobsd;
                    int ln = (nt < 13) ? nt : nt - 13;
                    half8 b = *(const half8*)(F + ((size_t)(ln * 7 + ks) * 64 + lane) * 8);
                    acc[j] = MFMA16(a, b, acc[j]);
                }
            }
            for (int j = 0; j < ntc; ++j) {
                int nt = nts[j];
                int colbase = (nt < 13) ? nt * 16 : 304 + (nt - 13) * 16;
#pragma unroll
                for (int i = 0; i < 4; ++i)
                    parts[(q * 4 + i) * 616 + colbase + m] = (_Float16)acc[j][i];
            }
        }
        __syncthreads();

        // pack h (elu(+img_b)) -> actH ; pack ho (elu(+obsout_b + ep)) -> actHO
        for (int idx = tid; idx < 3200; idx += 512) {
            int kind = idx / 1600, rem = idx - kind * 1600;
            int r = rem / 100, cp = rem % 100;
            if (kind == 0) {
                h2 v = *(const h2*)(parts + r * 616 + 2 * cp);
                float v0 = elu_((float)v[0] + bias[800 + 2 * cp]);
                float v1 = elu_((float)v[1] + bias[800 + 2 * cp + 1]);
                h2 p; p[0] = (_Float16)v0; p[1] = (_Float16)v1;
                *(h2*)&actH[r * 116 + cp] = p;
            } else {
                h2 v  = *(const h2*)(parts + r * 616 + 304 + 2 * cp);
                h2 e2 = *(const h2*)(ep + ((size_t)(rb + r) * 64 + t) * 208 + 2 * cp);
                float v0 = elu_((float)v[0] + bias[1000 + 2 * cp]     + (float)e2[0]);
                float v1 = elu_((float)v[1] + bias[1000 + 2 * cp + 1] + (float)e2[1]);
                h2 p; p[0] = (_Float16)v0; p[1] = (_Float16)v1;
                *(h2*)&actHO[r * 116 + cp] = p;
            }
        }
        __syncthreads();

        // P4: stats preacts: waves 0-3: h @ ims_W (cols 0..63) ; waves 4-7: ho @ obs_W (cols 304..367)
        {
            f32x4 acc = {};
            const unsigned* A = (w < 4) ? actH : actHO;
            const _Float16* F = (w < 4) ? Fims : Fobs;
            int nt = w & 3;
            for (int ks = 0; ks < 7; ++ks) {
                half8 a = *(const half8*)(A + m * 116 + ks * 16 + q * 4);
                half8 b = *(const half8*)(F + ((size_t)(nt * 7 + ks) * 64 + lane) * 8);
                acc = MFMA16(a, b, acc);
            }
            int colbase = ((w < 4) ? 0 : 304) + nt * 16;
#pragma unroll
            for (int i = 0; i < 4; ++i)
                parts[(q * 4 + i) * 616 + colbase + m] = (_Float16)acc[i];
        }
        __syncthreads();

        // P5: mean/std/stoch + output writes; posterior stoch -> actI pairs 0..14
        for (int idx = tid; idx < 480; idx += 512) {
            int side = idx / 240, rem = idx % 240;
            int r = rem / 15, cp = rem % 15;
            size_t ob = ((size_t)(rb + r) * 64 + t) * 380;
            int pbase = (side == 0) ? 0 : 304;
            int bb    = (side == 0) ? 1200 : 1260;
            h2 mh = *(const h2*)(parts + r * 616 + pbase + 2 * cp);
            h2 sh = *(const h2*)(parts + r * 616 + pbase + 30 + 2 * cp);
            float m0 = (float)mh[0] + bias[bb + 2 * cp];
            float m1 = (float)mh[1] + bias[bb + 2 * cp + 1];
            float s0 = sp_((float)sh[0] + bias[bb + 30 + 2 * cp]) + 0.1f;
            float s1 = sp_((float)sh[1] + bias[bb + 30 + 2 * cp + 1]) + 0.1f;
            const float* nsrc = (side == 0) ? npr : npo;
            float2 nz = *(const float2*)(nsrc + ((size_t)(rb + r) * 64 + t) * 30 + 2 * cp);
            float st0 = m0 + s0 * nz.x, st1 = m1 + s1 * nz.y;
            int o0 = (side == 0) ? 90 : 0;   // prior at 90/120/150, post at 0/30/60
            *(float2*)(out + ob + o0 + 2 * cp)      = make_float2(st0, st1);
            *(float2*)(out + ob + o0 + 30 + 2 * cp) = make_float2(m0, m1);
            *(float2*)(out + ob + o0 + 60 + 2 * cp) = make_float2(s0, s1);
            if (side == 1) {  // carry: stoch_po
                h2 pk; pk[0] = (_Float16)st0; pk[1] = (_Float16)st1;
                *(h2*)&actI[r * 36 + cp] = pk;
            }
        }
        __syncthreads();
    }
}

extern "C" void kernel_launch(void* const* d_in, const int* in_sizes, int n_in,
                              void* d_out, int out_size, void* d_ws, size_t ws_size,
                              hipStream_t stream) {
    const float* embed   = (const float*)d_in[0];
    const float* action  = (const float*)d_in[1];
    const float* npr     = (const float*)d_in[2];
    const float* npo     = (const float*)d_in[3];
    const float* inpW    = (const float*)d_in[4];
    const float* inpb    = (const float*)d_in[5];
    const float* gruW    = (const float*)d_in[6];
    const float* grub    = (const float*)d_in[7];
    const float* imgW    = (const float*)d_in[8];
    const float* imgb    = (const float*)d_in[9];
    const float* imsW    = (const float*)d_in[10];
    const float* imsb    = (const float*)d_in[11];
    const float* obsoutW = (const float*)d_in[12];
    const float* obsoutb = (const float*)d_in[13];
    const float* obsW    = (const float*)d_in[14];
    const float* obsb    = (const float*)d_in[15];

    _Float16* ep    = (_Float16*)d_ws;
    _Float16* frags = (_Float16*)d_ws + EP_HALVES;

    prep_frags<<<1174, 64, 0, stream>>>(inpW, gruW, imgW, obsoutW, imsW, obsW, frags);
    ep_gemm<<<2048, 256, 0, stream>>>(embed, frags + (size_t)758 * 512, ep);
    rssm_scan<<<32, 512, 0, stream>>>(action, npr, npo, inpb, grub, imgb, obsoutb,
                                      imsb, obsb, frags, ep, (float*)d_out);
}